// Round 1
// baseline (116.447 us; speedup 1.0000x reference)
//
#include <hip/hip_runtime.h>

// Problem constants (from reference):
//   BATCH=256, SEQ=512, VOCAB=100000, DIM=64, N_TABLES=3
//   inputs:    (256,512)  fp32 (integer-valued)
//   tables:    (3,100000,64) fp32
//   table_ids: (512,) int32, pattern [0,1,2,-1]
//   out:       (256,512,64) fp32
// out[b,s,:] = tables[table_ids[s], int(inputs[b,s]), :]  if table_ids[s]>=0
//            = inputs[b,s] broadcast over DIM             otherwise

#define SEQ   512
#define VOCAB 100000
#define DIM   64

__global__ __launch_bounds__(256) void
TransformerWord2VecEncoder_37804302139707_kernel(
    const float* __restrict__ inputs,     // [BATCH*SEQ]
    const float* __restrict__ tables,     // [3*VOCAB*DIM]
    const int*   __restrict__ table_ids,  // [SEQ]
    float*       __restrict__ out)        // [BATCH*SEQ*DIM]
{
    // 16 threads per row (each thread: one float4 = 16B), 16 rows per block.
    const int t    = blockIdx.x * 256 + threadIdx.x;
    const int r    = t >> 4;        // row index = b*SEQ + s
    const int lane = t & 15;        // float4 slot within the 64-float row

    const int   s   = r & (SEQ - 1);
    const float val = inputs[r];
    const int   tid = table_ids[s];

    float4 res;
    if (tid >= 0) {
        const int idx = (int)val;   // integer-valued fp32 index
        const float4* src =
            (const float4*)(tables + ((size_t)tid * VOCAB + (size_t)idx) * DIM);
        res = src[lane];
    } else {
        res = make_float4(val, val, val, val);
    }
    ((float4*)out)[(size_t)r * (DIM / 4) + lane] = res;
}

extern "C" void kernel_launch(void* const* d_in, const int* in_sizes, int n_in,
                              void* d_out, int out_size, void* d_ws, size_t ws_size,
                              hipStream_t stream) {
    const float* inputs    = (const float*)d_in[0];  // (256,512) fp32
    const float* tables    = (const float*)d_in[1];  // (3,100000,64) fp32
    const int*   table_ids = (const int*)d_in[2];    // (512,) int32
    float*       out       = (float*)d_out;          // (256,512,64) fp32

    // total threads = BATCH*SEQ*16 = 256*512*16 = 2,097,152 -> 8192 blocks of 256
    const int n_rows = out_size / DIM;               // 131072
    const int blocks = (n_rows * 16) / 256;          // 8192
    TransformerWord2VecEncoder_37804302139707_kernel<<<blocks, 256, 0, stream>>>(
        inputs, tables, table_ids, out);
}